// Round 3
// baseline (172.738 us; speedup 1.0000x reference)
//
#include <hip/hip_runtime.h>

// Problem geometry
#define TOT   19267584   // 128*768*14*14 == 128*3*224*224
#define MROWS 25088      // 128*196 patches
#define KD    768        // 3*16*16
#define NPB   196
#define CHW   150528     // 768*196
#define STRD  1204224    // 4704 blocks * 256 threads

typedef unsigned int uint;
typedef __attribute__((ext_vector_type(4))) int i32x4;

// workspace layout (bytes)
#define OFF_AQ   0ull              // int8 aq[25088*768] = 19,267,584 ; aliased later: int8 k1[TOT]
#define OFF_WQ   19267584ull       // int8 wq[768*768] = 589,824
#define OFF_WSC  19857408ull       // float w_scale[768]
#define OFF_INV  19860480ull       // float inv[768]
#define OFF_SHF  19863552ull       // float shift[768]
#define OFF_EMN  19866624ull       // uint enc(max(-y2)) [768]
#define OFF_EMX  19869696ull       // uint enc(max(y2))  [768]
#define OFF_SC   19872768ull       // uint sc[4]: max|x|, max|y_conv|, s2 bits, s3 bits

__device__ __forceinline__ float wave_max(float v) {
#pragma unroll
  for (int off = 32; off > 0; off >>= 1) v = fmaxf(v, __shfl_xor(v, off));
  return v;
}

__device__ __forceinline__ void block_max_atomic(float v, uint* dst) {
  __shared__ float red[4];
  v = wave_max(v);
  const int lane = threadIdx.x & 63, wv = threadIdx.x >> 6;
  if (lane == 0) red[wv] = v;
  __syncthreads();
  if (threadIdx.x == 0)
    atomicMax(dst, __float_as_uint(fmaxf(fmaxf(red[0], red[1]), fmaxf(red[2], red[3]))));
}

// order-preserving float<->uint encoding (for signed atomic max)
__device__ __forceinline__ uint enc(float f) {
  uint b = __float_as_uint(f);
  return (b & 0x80000000u) ? ~b : (b | 0x80000000u);
}
__device__ __forceinline__ float dec(uint k) {
  return __uint_as_float((k & 0x80000000u) ? (k & 0x7fffffffu) : ~k);
}

// ---------------- K0: global max|x| — 4 independent loads/thread, exact cover ----------------
__global__ void k_maxabs(const float* __restrict__ x, uint* __restrict__ sc) {
  const int i = blockIdx.x * 256 + threadIdx.x;
  const float4* x4 = (const float4*)x;
  float4 v0 = x4[i];
  float4 v1 = x4[i + STRD];
  float4 v2 = x4[i + 2 * STRD];
  float4 v3 = x4[i + 3 * STRD];
  float m = fmaxf(fmaxf(fmaxf(fabsf(v0.x), fabsf(v0.y)), fmaxf(fabsf(v0.z), fabsf(v0.w))),
                  fmaxf(fmaxf(fabsf(v1.x), fabsf(v1.y)), fmaxf(fabsf(v1.z), fabsf(v1.w))));
  m = fmaxf(m, fmaxf(fmaxf(fabsf(v2.x), fabsf(v2.y)), fmaxf(fabsf(v2.z), fabsf(v2.w))));
  m = fmaxf(m, fmaxf(fmaxf(fabsf(v3.x), fabsf(v3.y)), fmaxf(fabsf(v3.z), fabsf(v3.w))));
  block_max_atomic(m, sc + 0);
}

// ---------------- K1: weight quant (per-oc, int8) + BN coefficients ----------------
__global__ void k_wquant(const float* __restrict__ W, const float* __restrict__ gamma,
                         const float* __restrict__ beta, const float* __restrict__ rmean,
                         const float* __restrict__ rvar, signed char* __restrict__ wq,
                         float* __restrict__ wscale, float* __restrict__ inv_,
                         float* __restrict__ shf) {
  const int oc = blockIdx.x;
  const float* row = W + oc * KD;
  float m = 0.f;
  for (int k = threadIdx.x; k < KD; k += 256) m = fmaxf(m, fabsf(row[k]));
  __shared__ float red[4];
  m = wave_max(m);
  if ((threadIdx.x & 63) == 0) red[threadIdx.x >> 6] = m;
  __syncthreads();
  const float ws_ = fmaxf(fmaxf(red[0], red[1]), fmaxf(red[2], red[3])) / 127.0f;
  for (int k = threadIdx.x; k < KD; k += 256)
    wq[oc * KD + k] = (signed char)(int)rintf(row[k] / ws_);
  if (threadIdx.x == 0) {
    wscale[oc] = ws_;
    float iv = gamma[oc] / sqrtf(rvar[oc] + 1e-5f);
    inv_[oc] = iv;
    shf[oc] = __fsub_rn(beta[oc], __fmul_rn(rmean[oc], iv));  // jax: mul then sub, no fma
  }
}

// ---------------- K2: im2col + quant; one 16-float patch row per thread ----------------
__global__ void k_im2col(const float* __restrict__ x, const uint* __restrict__ sc,
                         signed char* __restrict__ aq) {
  const float ps = __uint_as_float(sc[0]) / 127.0f;
  const int u = blockIdx.x * 256 + threadIdx.x;   // u < 1,204,224 = 25088*48 exact
  const int p = u / 48, r = u - p * 48;           // patch, (c,kh) row
  const int c = r >> 4, kh = r & 15;
  const int b = p / NPB, pp = p - b * NPB;
  const int ph = pp / 14, pw = pp - ph * 14;
  const float* src = x + (((b * 3 + c) * 224 + ph * 16 + kh) * 224 + pw * 16);
  float4 v0 = *(const float4*)(src);
  float4 v1 = *(const float4*)(src + 4);
  float4 v2 = *(const float4*)(src + 8);
  float4 v3 = *(const float4*)(src + 12);
#define Q8(v) ((int)fminf(fmaxf(rintf((v) / ps), -127.f), 127.f) & 255)
  uint4 o;
  o.x = Q8(v0.x) | (Q8(v0.y) << 8) | (Q8(v0.z) << 16) | ((uint)Q8(v0.w) << 24);
  o.y = Q8(v1.x) | (Q8(v1.y) << 8) | (Q8(v1.z) << 16) | ((uint)Q8(v1.w) << 24);
  o.z = Q8(v2.x) | (Q8(v2.y) << 8) | (Q8(v2.z) << 16) | ((uint)Q8(v2.w) << 24);
  o.w = Q8(v3.x) | (Q8(v3.y) << 8) | (Q8(v3.z) << 16) | ((uint)Q8(v3.w) << 24);
#undef Q8
  *(uint4*)(aq + (size_t)p * KD + (r << 4)) = o;
}

// ---------------- K3: i8 MFMA GEMM, 2-phase dbuf, XOR-swizzled LDS ----------------
__device__ __forceinline__ void gl_lds16(const void* g, void* l) {
  __builtin_amdgcn_global_load_lds((const __attribute__((address_space(1))) void*)g,
                                   (__attribute__((address_space(3))) void*)l, 16, 0, 0);
}

__global__ __launch_bounds__(256) void k_gemm(const signed char* __restrict__ aq,
                                              const signed char* __restrict__ wq,
                                              const float* __restrict__ bias,
                                              const float* __restrict__ wscale,
                                              uint* __restrict__ sc,
                                              float* __restrict__ y) {
  __shared__ __align__(16) signed char lA[2][8192];   // 128 rows x 64 K (i8), dbuf
  __shared__ __align__(16) signed char lB[2][8192];
  const int tid = threadIdx.x, lane = tid & 63, wv = tid >> 6;
  // XCD-aware swizzle (1176 = 8*147, bijective) + bn-inner for A-tile L2 reuse
  const int bsw = (blockIdx.x & 7) * 147 + (blockIdx.x >> 3);
  const int bm = bsw / 6, bn = bsw - 6 * (bsw / 6);
  const int wr = wv >> 1, wc = wv & 1;               // 2x2 waves, 64x64 each
  const float ps = __uint_as_float(sc[0]) / 127.0f;

  // staging: 8192B tile = 8 chunks of 1024B (16 rows x 64B); rule-21 swizzle:
  // LDS dest linear; SOURCE k-offset XOR'd by (row&3)<<4 (involution, 16B granular)
  const int ci0 = wv * 2, ci1 = wv * 2 + 1;
  const int rr0 = ci0 * 16 + (lane >> 2);
  const int rr1 = ci1 * 16 + (lane >> 2);
  const int bo = (((lane & 3) ^ ((lane >> 2) & 3)) << 4);
  const signed char* gA0 = aq + (size_t)(bm * 128 + rr0) * KD + bo;
  const signed char* gA1 = aq + (size_t)(bm * 128 + rr1) * KD + bo;
  const signed char* gB0 = wq + (size_t)(bn * 128 + rr0) * KD + bo;
  const signed char* gB1 = wq + (size_t)(bn * 128 + rr1) * KD + bo;

  i32x4 acc[4][4];
#pragma unroll
  for (int m = 0; m < 4; ++m)
#pragma unroll
    for (int n = 0; n < 4; ++n) acc[m][n] = (i32x4){0, 0, 0, 0};

  const int rbase = lane & 15;
  // swizzled ds_read k-offset: row&3 == lane&3 for every fragment row we touch
  const int kg = (((lane >> 4) << 4)) ^ ((lane & 3) << 4);

  // prologue: stage tile 0
  gl_lds16(gA0, &lA[0][ci0 * 1024]);
  gl_lds16(gA1, &lA[0][ci1 * 1024]);
  gl_lds16(gB0, &lB[0][ci0 * 1024]);
  gl_lds16(gB1, &lB[0][ci1 * 1024]);
  __syncthreads();

  int cur = 0;
  for (int t = 0; t < 12; ++t) {
    if (t < 11) {                                    // prefetch next K-tile into other buffer
      const int kk = (t + 1) * 64;
      gl_lds16(gA0 + kk, &lA[cur ^ 1][ci0 * 1024]);
      gl_lds16(gA1 + kk, &lA[cur ^ 1][ci1 * 1024]);
      gl_lds16(gB0 + kk, &lB[cur ^ 1][ci0 * 1024]);
      gl_lds16(gB1 + kk, &lB[cur ^ 1][ci1 * 1024]);
    }
    i32x4 af[4], bfr[4];
#pragma unroll
    for (int m = 0; m < 4; ++m)
      af[m] = *(const i32x4*)&lA[cur][(wr * 64 + m * 16 + rbase) * 64 + kg];
#pragma unroll
    for (int n = 0; n < 4; ++n)
      bfr[n] = *(const i32x4*)&lB[cur][(wc * 64 + n * 16 + rbase) * 64 + kg];
#pragma unroll
    for (int m = 0; m < 4; ++m)
#pragma unroll
      for (int n = 0; n < 4; ++n)
        acc[m][n] = __builtin_amdgcn_mfma_i32_16x16x64_i8(af[m], bfr[n], acc[m][n], 0, 0, 0);
    __syncthreads();   // drains vmcnt (prefetch landed) + lgkm; buffers swap safely
    cur ^= 1;
  }

  // epilogue: y = (acc + b_int) * comb_s, final [B,768,14,14] layout
  float lmax = 0.f;
  const int prow = (lane >> 4) << 2;
#pragma unroll
  for (int n = 0; n < 4; ++n) {
    const int oc = bn * 128 + wc * 64 + n * 16 + rbase;
    const float comb = wscale[oc] * ps;
    const float bint = rintf(bias[oc] / comb);
#pragma unroll
    for (int m = 0; m < 4; ++m) {
      const int p0 = bm * 128 + wr * 64 + m * 16 + prow;  // 4-aligned; stays within one image
      const int img = p0 / 196;
      const int q = p0 - img * 196;
      float4 o;
      o.x = ((float)acc[m][n][0] + bint) * comb;
      o.y = ((float)acc[m][n][1] + bint) * comb;
      o.z = ((float)acc[m][n][2] + bint) * comb;
      o.w = ((float)acc[m][n][3] + bint) * comb;
      lmax = fmaxf(lmax, fmaxf(fmaxf(fabsf(o.x), fabsf(o.y)), fmaxf(fabsf(o.z), fabsf(o.w))));
      *(float4*)(y + (size_t)img * CHW + (size_t)oc * 196 + q) = o;
    }
  }
  block_max_atomic(lmax, sc + 1);
}

// ---------------- K4: gelu pass: write k1, per-channel min/max of y2 (2 blocks/chan) ----------------
__global__ void k_gelu_chan(const float* __restrict__ y, const uint* __restrict__ sc,
                            signed char* __restrict__ k1, uint* __restrict__ emn,
                            uint* __restrict__ emx) {
  const int c = blockIdx.x >> 1, half = blockIdx.x & 1;
  const float s1 = __uint_as_float(sc[1]) / 127.0f;
  __shared__ float tab[255];
  for (int t = threadIdx.x; t < 255; t += 256) {
    float y1 = (float)(t - 127) * s1;
    float e = erff(y1 * 0.70710678118654752f);
    tab[t] = (y1 * (e + 1.0f)) * 0.5f;
  }
  __syncthreads();
  float mn = 1e30f, mx = -1e30f;
  const float4* y4 = (const float4*)y;
  char4* k4 = (char4*)k1;
  const int imgbase = half * 64;
  // 64 imgs * 49 float4 = 3136 elems = 12*256 + 64
#define ADDR(u) ((size_t)(imgbase + (u) / 49) * (CHW / 4) + (size_t)c * 49 + ((u) - ((u) / 49) * 49))
#define PROC(v, a4)                                                        \
  {                                                                        \
    int ia = (int)fminf(fmaxf(rintf((v).x / s1), -127.f), 127.f);          \
    int ib = (int)fminf(fmaxf(rintf((v).y / s1), -127.f), 127.f);          \
    int ic = (int)fminf(fmaxf(rintf((v).z / s1), -127.f), 127.f);          \
    int id = (int)fminf(fmaxf(rintf((v).w / s1), -127.f), 127.f);          \
    char4 kk;                                                              \
    kk.x = (signed char)ia; kk.y = (signed char)ib;                        \
    kk.z = (signed char)ic; kk.w = (signed char)id;                        \
    k4[a4] = kk;                                                           \
    float ga = tab[ia + 127], gb = tab[ib + 127];                          \
    float gc = tab[ic + 127], gd = tab[id + 127];                          \
    mn = fminf(mn, fminf(fminf(ga, gb), fminf(gc, gd)));                   \
    mx = fmaxf(mx, fmaxf(fmaxf(ga, gb), fmaxf(gc, gd)));                   \
  }
  for (int r = 0; r < 3; ++r) {
    const int u0 = threadIdx.x + r * 1024;
    const size_t a0 = ADDR(u0), a1 = ADDR(u0 + 256), a2 = ADDR(u0 + 512), a3 = ADDR(u0 + 768);
    float4 v0 = y4[a0];
    float4 v1 = y4[a1];
    float4 v2 = y4[a2];
    float4 v3 = y4[a3];
    PROC(v0, a0) PROC(v1, a1) PROC(v2, a2) PROC(v3, a3)
  }
  if (threadIdx.x < 64) {
    const int u = 3072 + threadIdx.x;
    const size_t a = ADDR(u);
    float4 v = y4[a];
    PROC(v, a)
  }
#undef PROC
#undef ADDR
  __shared__ float rmn[4], rmx[4];
#pragma unroll
  for (int off = 32; off > 0; off >>= 1) {
    mn = fminf(mn, __shfl_xor(mn, off));
    mx = fmaxf(mx, __shfl_xor(mx, off));
  }
  const int lane = threadIdx.x & 63, wvx = threadIdx.x >> 6;
  if (lane == 0) { rmn[wvx] = mn; rmx[wvx] = mx; }
  __syncthreads();
  if (threadIdx.x == 0) {
    float bmn = fminf(fminf(rmn[0], rmn[1]), fminf(rmn[2], rmn[3]));
    float bmx = fmaxf(fmaxf(rmx[0], rmx[1]), fmaxf(rmx[2], rmx[3]));
    atomicMax(&emn[c], enc(-bmn));
    atomicMax(&emx[c], enc(bmx));
  }
}

// ---------------- K5: scales from channel extremes (monotone chain => exact) ----------------
__global__ void k_scales(const uint* __restrict__ emn, const uint* __restrict__ emx,
                         const float* __restrict__ inv_, const float* __restrict__ shf,
                         uint* __restrict__ sc) {
  __shared__ float sred[4];
  __shared__ float s2sh;
  const int tid = threadIdx.x;
  float m2 = 0.f;
  for (int c = tid; c < 768; c += 256) {
    float mn = -dec(emn[c]), mx = dec(emx[c]);
    m2 = fmaxf(m2, fmaxf(fabsf(mn), fabsf(mx)));
  }
  m2 = wave_max(m2);
  if ((tid & 63) == 0) sred[tid >> 6] = m2;
  __syncthreads();
  if (tid == 0) {
    float s2 = fmaxf(fmaxf(sred[0], sred[1]), fmaxf(sred[2], sred[3])) / 127.0f;
    s2sh = s2;
    sc[2] = __float_as_uint(s2);
  }
  __syncthreads();
  const float s2 = s2sh;
  float m4 = 0.f;
  for (int c = tid; c < 768; c += 256) {
    float mn = -dec(emn[c]), mx = dec(emx[c]);
    float iv = inv_[c], sh = shf[c];
    float a = fminf(fmaxf(rintf(mn / s2), -127.f), 127.f) * s2;
    float b = fminf(fmaxf(rintf(mx / s2), -127.f), 127.f) * s2;
    float ya = __fadd_rn(__fmul_rn(a, iv), sh);
    float yb = __fadd_rn(__fmul_rn(b, iv), sh);
    m4 = fmaxf(m4, fmaxf(fabsf(ya), fabsf(yb)));
  }
  m4 = wave_max(m4);
  __syncthreads();
  if ((tid & 63) == 0) sred[tid >> 6] = m4;
  __syncthreads();
  if (tid == 0)
    sc[3] = __float_as_uint(fmaxf(fmaxf(sred[0], sred[1]), fmaxf(sred[2], sred[3])) / 127.0f);
}

// ---------------- K6: final quant-dequant write + act_scale (4 indep loads) ----------------
__global__ void k_final(const signed char* __restrict__ k1, const uint* __restrict__ sc,
                        const float* __restrict__ inv_, const float* __restrict__ shf,
                        float* __restrict__ out) {
  __shared__ float tab[255];
  const float s1 = __uint_as_float(sc[1]) / 127.0f;
  const float s2 = __uint_as_float(sc[2]);
  const float s3 = __uint_as_float(sc[3]);
  for (int t = threadIdx.x; t < 255; t += 256) {
    float y1 = (float)(t - 127) * s1;
    float e = erff(y1 * 0.70710678118654752f);
    float y2 = (y1 * (e + 1.0f)) * 0.5f;
    float q2 = fminf(fmaxf(rintf(y2 / s2), -127.f), 127.f);
    tab[t] = q2 * s2;
  }
  __syncthreads();
  const int i = blockIdx.x * 256 + threadIdx.x;
  const char4* k4 = (const char4*)k1;
  char4 a0 = k4[i];
  char4 a1 = k4[i + STRD];
  char4 a2 = k4[i + 2 * STRD];
  char4 a3 = k4[i + 3 * STRD];
  float4* out4 = (float4*)out;
#define FIN(kk, idx)                                                       \
  {                                                                        \
    int c = ((idx) / 49) % 768;                                            \
    float iv = inv_[c], sh = shf[c];                                       \
    float fa = __fadd_rn(__fmul_rn(tab[kk.x + 127], iv), sh);              \
    float fb = __fadd_rn(__fmul_rn(tab[kk.y + 127], iv), sh);              \
    float fc = __fadd_rn(__fmul_rn(tab[kk.z + 127], iv), sh);              \
    float fd = __fadd_rn(__fmul_rn(tab[kk.w + 127], iv), sh);              \
    float4 o;                                                              \
    o.x = fminf(fmaxf(rintf(fa / s3), -127.f), 127.f) * s3;                \
    o.y = fminf(fmaxf(rintf(fb / s3), -127.f), 127.f) * s3;                \
    o.z = fminf(fmaxf(rintf(fc / s3), -127.f), 127.f) * s3;                \
    o.w = fminf(fmaxf(rintf(fd / s3), -127.f), 127.f) * s3;                \
    out4[idx] = o;                                                         \
  }
  FIN(a0, i)
  FIN(a1, i + STRD)
  FIN(a2, i + 2 * STRD)
  FIN(a3, i + 3 * STRD)
#undef FIN
  if (blockIdx.x == 0 && threadIdx.x == 0) out[TOT] = s3;  // act_scale
}

extern "C" void kernel_launch(void* const* d_in, const int* in_sizes, int n_in,
                              void* d_out, int out_size, void* d_ws, size_t ws_size,
                              hipStream_t stream) {
  const float* x     = (const float*)d_in[0];
  const float* W     = (const float*)d_in[1];
  const float* bias  = (const float*)d_in[2];
  const float* gamma = (const float*)d_in[3];
  const float* beta  = (const float*)d_in[4];
  const float* rmean = (const float*)d_in[5];
  const float* rvar  = (const float*)d_in[6];
  float* out = (float*)d_out;
  char* ws = (char*)d_ws;

  signed char* aq  = (signed char*)(ws + OFF_AQ);
  signed char* wq  = (signed char*)(ws + OFF_WQ);
  float* wsc  = (float*)(ws + OFF_WSC);
  float* inv_ = (float*)(ws + OFF_INV);
  float* shf  = (float*)(ws + OFF_SHF);
  uint*  emn  = (uint*)(ws + OFF_EMN);
  uint*  emx  = (uint*)(ws + OFF_EMX);
  uint*  sc   = (uint*)(ws + OFF_SC);
  signed char* k1 = (signed char*)(ws + OFF_AQ);  // aliases aq (dead after GEMM)

  hipMemsetAsync(ws + OFF_EMN, 0, 6160, stream);  // emn, emx, sc
  k_maxabs<<<4704, 256, 0, stream>>>(x, sc);
  k_wquant<<<768, 256, 0, stream>>>(W, gamma, beta, rmean, rvar, wq, wsc, inv_, shf);
  k_im2col<<<4704, 256, 0, stream>>>(x, sc, aq);
  k_gemm<<<1176, 256, 0, stream>>>(aq, wq, bias, wsc, sc, out);
  k_gelu_chan<<<1536, 256, 0, stream>>>(out, sc, k1, emn, emx);
  k_scales<<<1, 256, 0, stream>>>(emn, emx, inv_, shf, sc);
  k_final<<<4704, 256, 0, stream>>>(k1, sc, inv_, shf, out);
}

// Round 4
// 124.781 us; speedup vs baseline: 1.3843x; 1.3843x over previous
//
#include <hip/hip_runtime.h>

// Problem geometry
#define TOT   19267584   // 128*768*14*14 == 128*3*224*224
#define MROWS 25088      // 128*196 patches
#define KD    768        // 3*16*16
#define NPB   196
#define CHW   150528     // 768*196

typedef unsigned int uint;
typedef __attribute__((ext_vector_type(4))) int i32x4;

// workspace layout (bytes)
#define OFF_AQ   0ull              // int8 aq[25088*768] = 19,267,584 ; aliased later: int8 k1[TOT]
#define OFF_WQ   19267584ull       // int8 wq[768*768] = 589,824
#define OFF_WSC  19857408ull       // float w_scale[768]
#define OFF_INV  19860480ull       // float inv[768]
#define OFF_SHF  19863552ull       // float shift[768]
#define OFF_PA   19866624ull       // float pA[1176]  (maxabs partials)
#define OFF_PB   19871328ull       // float pB[1176]  (gemm |y| partials)
#define OFF_CMN  19876032ull       // float chmin[768]
#define OFF_CMX  19879104ull       // float chmax[768]
#define OFF_SC   19882176ull       // uint sc[4]: max|x|, max|y_conv|, s2 bits, s3 bits

__device__ __forceinline__ float wave_max(float v) {
#pragma unroll
  for (int off = 32; off > 0; off >>= 1) v = fmaxf(v, __shfl_xor(v, off));
  return v;
}

// block max, valid in all threads after return (no atomics)
__device__ __forceinline__ float block_max(float v) {
  __shared__ float red[4];
  v = wave_max(v);
  if ((threadIdx.x & 63) == 0) red[threadIdx.x >> 6] = v;
  __syncthreads();
  return fmaxf(fmaxf(red[0], red[1]), fmaxf(red[2], red[3]));
}

// ---------------- K0: max|x| partials — 16 loads/thread, plain partial store ----------------
__global__ void k_maxabs(const float* __restrict__ x, float* __restrict__ pA) {
  const int i0 = blockIdx.x * 256 + threadIdx.x;   // 1176 blocks; 1176*256*16 = TOT/4 exact
  const float4* x4 = (const float4*)x;
  float m = 0.f;
#pragma unroll
  for (int j = 0; j < 16; j += 4) {
    float4 a = x4[i0 + (j + 0) * 301056];
    float4 b = x4[i0 + (j + 1) * 301056];
    float4 c = x4[i0 + (j + 2) * 301056];
    float4 d = x4[i0 + (j + 3) * 301056];
    m = fmaxf(m, fmaxf(fmaxf(fabsf(a.x), fabsf(a.y)), fmaxf(fabsf(a.z), fabsf(a.w))));
    m = fmaxf(m, fmaxf(fmaxf(fabsf(b.x), fabsf(b.y)), fmaxf(fabsf(b.z), fabsf(b.w))));
    m = fmaxf(m, fmaxf(fmaxf(fabsf(c.x), fabsf(c.y)), fmaxf(fabsf(c.z), fabsf(c.w))));
    m = fmaxf(m, fmaxf(fmaxf(fabsf(d.x), fabsf(d.y)), fmaxf(fabsf(d.z), fabsf(d.w))));
  }
  float bm = block_max(m);
  if (threadIdx.x == 0) pA[blockIdx.x] = bm;
}

// ---------------- combine: sc[k] = max of n partials (single block) ----------------
__global__ void k_combine(const float* __restrict__ p, int n, uint* __restrict__ dst) {
  float m = 0.f;
  for (int i = threadIdx.x; i < n; i += 256) m = fmaxf(m, p[i]);
  float bm = block_max(m);
  if (threadIdx.x == 0) *dst = __float_as_uint(bm);
}

// ---------------- K1: weight quant (per-oc, int8) + BN coefficients ----------------
__global__ void k_wquant(const float* __restrict__ W, const float* __restrict__ gamma,
                         const float* __restrict__ beta, const float* __restrict__ rmean,
                         const float* __restrict__ rvar, signed char* __restrict__ wq,
                         float* __restrict__ wscale, float* __restrict__ inv_,
                         float* __restrict__ shf) {
  const int oc = blockIdx.x;
  const float* row = W + oc * KD;
  float m = 0.f;
  for (int k = threadIdx.x; k < KD; k += 256) m = fmaxf(m, fabsf(row[k]));
  const float ws_ = block_max(m) / 127.0f;
  for (int k = threadIdx.x; k < KD; k += 256)
    wq[oc * KD + k] = (signed char)(int)rintf(row[k] / ws_);
  if (threadIdx.x == 0) {
    wscale[oc] = ws_;
    float iv = gamma[oc] / sqrtf(rvar[oc] + 1e-5f);
    inv_[oc] = iv;
    shf[oc] = __fsub_rn(beta[oc], __fmul_rn(rmean[oc], iv));  // jax: mul then sub, no fma
  }
}

// ---------------- K2: im2col + quant; one 16-float patch row per thread ----------------
__global__ void k_im2col(const float* __restrict__ x, const uint* __restrict__ sc,
                         signed char* __restrict__ aq) {
  const float ps = __uint_as_float(sc[0]) / 127.0f;
  const int u = blockIdx.x * 256 + threadIdx.x;   // u < 1,204,224 = 25088*48 exact
  const int p = u / 48, r = u - p * 48;           // patch, (c,kh) row
  const int c = r >> 4, kh = r & 15;
  const int b = p / NPB, pp = p - b * NPB;
  const int ph = pp / 14, pw = pp - ph * 14;
  const float* src = x + (((b * 3 + c) * 224 + ph * 16 + kh) * 224 + pw * 16);
  float4 v0 = *(const float4*)(src);
  float4 v1 = *(const float4*)(src + 4);
  float4 v2 = *(const float4*)(src + 8);
  float4 v3 = *(const float4*)(src + 12);
#define Q8(v) ((int)fminf(fmaxf(rintf((v) / ps), -127.f), 127.f) & 255)
  uint4 o;
  o.x = Q8(v0.x) | (Q8(v0.y) << 8) | (Q8(v0.z) << 16) | ((uint)Q8(v0.w) << 24);
  o.y = Q8(v1.x) | (Q8(v1.y) << 8) | (Q8(v1.z) << 16) | ((uint)Q8(v1.w) << 24);
  o.z = Q8(v2.x) | (Q8(v2.y) << 8) | (Q8(v2.z) << 16) | ((uint)Q8(v2.w) << 24);
  o.w = Q8(v3.x) | (Q8(v3.y) << 8) | (Q8(v3.z) << 16) | ((uint)Q8(v3.w) << 24);
#undef Q8
  *(uint4*)(aq + (size_t)p * KD + (r << 4)) = o;
}

// ---------------- K3: i8 MFMA GEMM, 2-phase dbuf, XOR-swizzled LDS ----------------
__device__ __forceinline__ void gl_lds16(const void* g, void* l) {
  __builtin_amdgcn_global_load_lds((const __attribute__((address_space(1))) void*)g,
                                   (__attribute__((address_space(3))) void*)l, 16, 0, 0);
}

__global__ __launch_bounds__(256) void k_gemm(const signed char* __restrict__ aq,
                                              const signed char* __restrict__ wq,
                                              const float* __restrict__ bias,
                                              const float* __restrict__ wscale,
                                              const uint* __restrict__ sc,
                                              float* __restrict__ y,
                                              float* __restrict__ pB) {
  __shared__ __align__(16) signed char lA[2][8192];   // 128 rows x 64 K (i8), dbuf
  __shared__ __align__(16) signed char lB[2][8192];
  const int tid = threadIdx.x, lane = tid & 63, wv = tid >> 6;
  // XCD-aware swizzle (1176 = 8*147, bijective) + bn-inner for A-tile L2 reuse
  const int bsw = (blockIdx.x & 7) * 147 + (blockIdx.x >> 3);
  const int bm = bsw / 6, bn = bsw - 6 * (bsw / 6);
  const int wr = wv >> 1, wc = wv & 1;               // 2x2 waves, 64x64 each
  const float ps = __uint_as_float(sc[0]) / 127.0f;

  // staging: 8192B tile = 8 chunks of 1024B (16 rows x 64B); rule-21 swizzle:
  // LDS dest linear; SOURCE k-offset XOR'd by (row&3)<<4 (involution, 16B granular)
  const int ci0 = wv * 2, ci1 = wv * 2 + 1;
  const int rr0 = ci0 * 16 + (lane >> 2);
  const int rr1 = ci1 * 16 + (lane >> 2);
  const int bo = (((lane & 3) ^ ((lane >> 2) & 3)) << 4);
  const signed char* gA0 = aq + (size_t)(bm * 128 + rr0) * KD + bo;
  const signed char* gA1 = aq + (size_t)(bm * 128 + rr1) * KD + bo;
  const signed char* gB0 = wq + (size_t)(bn * 128 + rr0) * KD + bo;
  const signed char* gB1 = wq + (size_t)(bn * 128 + rr1) * KD + bo;

  i32x4 acc[4][4];
#pragma unroll
  for (int m = 0; m < 4; ++m)
#pragma unroll
    for (int n = 0; n < 4; ++n) acc[m][n] = (i32x4){0, 0, 0, 0};

  const int rbase = lane & 15;
  // swizzled ds_read k-offset: row&3 == lane&3 for every fragment row we touch
  const int kg = (((lane >> 4) << 4)) ^ ((lane & 3) << 4);

  // prologue: stage tile 0
  gl_lds16(gA0, &lA[0][ci0 * 1024]);
  gl_lds16(gA1, &lA[0][ci1 * 1024]);
  gl_lds16(gB0, &lB[0][ci0 * 1024]);
  gl_lds16(gB1, &lB[0][ci1 * 1024]);
  __syncthreads();

  int cur = 0;
  for (int t = 0; t < 12; ++t) {
    if (t < 11) {                                    // prefetch next K-tile into other buffer
      const int kk = (t + 1) * 64;
      gl_lds16(gA0 + kk, &lA[cur ^ 1][ci0 * 1024]);
      gl_lds16(gA1 + kk, &lA[cur ^ 1][ci1 * 1024]);
      gl_lds16(gB0 + kk, &lB[cur ^ 1][ci0 * 1024]);
      gl_lds16(gB1 + kk, &lB[cur ^ 1][ci1 * 1024]);
    }
    i32x4 af[4], bfr[4];
#pragma unroll
    for (int m = 0; m < 4; ++m)
      af[m] = *(const i32x4*)&lA[cur][(wr * 64 + m * 16 + rbase) * 64 + kg];
#pragma unroll
    for (int n = 0; n < 4; ++n)
      bfr[n] = *(const i32x4*)&lB[cur][(wc * 64 + n * 16 + rbase) * 64 + kg];
#pragma unroll
    for (int m = 0; m < 4; ++m)
#pragma unroll
      for (int n = 0; n < 4; ++n)
        acc[m][n] = __builtin_amdgcn_mfma_i32_16x16x64_i8(af[m], bfr[n], acc[m][n], 0, 0, 0);
    __syncthreads();   // drains vmcnt (prefetch landed) + lgkm; buffers swap safely
    cur ^= 1;
  }

  // epilogue: y = (acc + b_int) * comb_s, final [B,768,14,14] layout
  float lmax = 0.f;
  const int prow = (lane >> 4) << 2;
#pragma unroll
  for (int n = 0; n < 4; ++n) {
    const int oc = bn * 128 + wc * 64 + n * 16 + rbase;
    const float comb = wscale[oc] * ps;
    const float bint = rintf(bias[oc] / comb);
#pragma unroll
    for (int m = 0; m < 4; ++m) {
      const int p0 = bm * 128 + wr * 64 + m * 16 + prow;  // 4-aligned; stays within one image
      const int img = p0 / 196;
      const int q = p0 - img * 196;
      float4 o;
      o.x = ((float)acc[m][n][0] + bint) * comb;
      o.y = ((float)acc[m][n][1] + bint) * comb;
      o.z = ((float)acc[m][n][2] + bint) * comb;
      o.w = ((float)acc[m][n][3] + bint) * comb;
      lmax = fmaxf(lmax, fmaxf(fmaxf(fabsf(o.x), fabsf(o.y)), fmaxf(fabsf(o.z), fabsf(o.w))));
      *(float4*)(y + (size_t)img * CHW + (size_t)oc * 196 + q) = o;
    }
  }
  float bm_ = block_max(lmax);
  if (tid == 0) pB[blockIdx.x] = bm_;
}

// ---------------- K4: gelu pass: write k1, per-channel min/max (1 block/channel) ----------------
__global__ void k_gelu_chan(const float* __restrict__ y, const uint* __restrict__ sc,
                            signed char* __restrict__ k1, float* __restrict__ chmn,
                            float* __restrict__ chmx) {
  const int c = blockIdx.x;
  const float s1 = __uint_as_float(sc[1]) / 127.0f;
  __shared__ float tab[255];
  for (int t = threadIdx.x; t < 255; t += 256) {
    float y1 = (float)(t - 127) * s1;
    float e = erff(y1 * 0.70710678118654752f);
    tab[t] = (y1 * (e + 1.0f)) * 0.5f;
  }
  __syncthreads();
  float mn = 1e30f, mx = -1e30f;
  const float4* y4 = (const float4*)y;
  char4* k4 = (char4*)k1;
  // 128 imgs * 49 float4 = 6272 = 6*1024 + 128
#define ADDR(u) ((size_t)((u) / 49) * (CHW / 4) + (size_t)c * 49 + ((u) - ((u) / 49) * 49))
#define PROC(v, a4)                                                        \
  {                                                                        \
    int ia = (int)fminf(fmaxf(rintf((v).x / s1), -127.f), 127.f);          \
    int ib = (int)fminf(fmaxf(rintf((v).y / s1), -127.f), 127.f);          \
    int ic = (int)fminf(fmaxf(rintf((v).z / s1), -127.f), 127.f);          \
    int id = (int)fminf(fmaxf(rintf((v).w / s1), -127.f), 127.f);          \
    char4 kk;                                                              \
    kk.x = (signed char)ia; kk.y = (signed char)ib;                        \
    kk.z = (signed char)ic; kk.w = (signed char)id;                        \
    k4[a4] = kk;                                                           \
    float ga = tab[ia + 127], gb = tab[ib + 127];                          \
    float gc = tab[ic + 127], gd = tab[id + 127];                          \
    mn = fminf(mn, fminf(fminf(ga, gb), fminf(gc, gd)));                   \
    mx = fmaxf(mx, fmaxf(fmaxf(ga, gb), fmaxf(gc, gd)));                   \
  }
  for (int r = 0; r < 6; ++r) {
    const int u0 = threadIdx.x + r * 1024;
    const size_t a0 = ADDR(u0), a1 = ADDR(u0 + 256), a2 = ADDR(u0 + 512), a3 = ADDR(u0 + 768);
    float4 v0 = y4[a0];
    float4 v1 = y4[a1];
    float4 v2 = y4[a2];
    float4 v3 = y4[a3];
    PROC(v0, a0) PROC(v1, a1) PROC(v2, a2) PROC(v3, a3)
  }
  if (threadIdx.x < 128) {
    const int u = 6144 + threadIdx.x;
    const size_t a = ADDR(u);
    float4 v = y4[a];
    PROC(v, a)
  }
#undef PROC
#undef ADDR
  __shared__ float rmn[4], rmx[4];
#pragma unroll
  for (int off = 32; off > 0; off >>= 1) {
    mn = fminf(mn, __shfl_xor(mn, off));
    mx = fmaxf(mx, __shfl_xor(mx, off));
  }
  const int lane = threadIdx.x & 63, wvx = threadIdx.x >> 6;
  if (lane == 0) { rmn[wvx] = mn; rmx[wvx] = mx; }
  __syncthreads();
  if (threadIdx.x == 0) {
    chmn[c] = fminf(fminf(rmn[0], rmn[1]), fminf(rmn[2], rmn[3]));
    chmx[c] = fmaxf(fmaxf(rmx[0], rmx[1]), fmaxf(rmx[2], rmx[3]));
  }
}

// ---------------- K5: scales from channel extremes (monotone chain => exact) ----------------
__global__ void k_scales(const float* __restrict__ chmn, const float* __restrict__ chmx,
                         const float* __restrict__ inv_, const float* __restrict__ shf,
                         uint* __restrict__ sc) {
  __shared__ float sred[4];
  __shared__ float s2sh;
  const int tid = threadIdx.x;
  float m2 = 0.f;
  for (int c = tid; c < 768; c += 256)
    m2 = fmaxf(m2, fmaxf(fabsf(chmn[c]), fabsf(chmx[c])));
  m2 = wave_max(m2);
  if ((tid & 63) == 0) sred[tid >> 6] = m2;
  __syncthreads();
  if (tid == 0) {
    float s2 = fmaxf(fmaxf(sred[0], sred[1]), fmaxf(sred[2], sred[3])) / 127.0f;
    s2sh = s2;
    sc[2] = __float_as_uint(s2);
  }
  __syncthreads();
  const float s2 = s2sh;
  float m4 = 0.f;
  for (int c = tid; c < 768; c += 256) {
    float iv = inv_[c], sh = shf[c];
    float a = fminf(fmaxf(rintf(chmn[c] / s2), -127.f), 127.f) * s2;
    float b = fminf(fmaxf(rintf(chmx[c] / s2), -127.f), 127.f) * s2;
    float ya = __fadd_rn(__fmul_rn(a, iv), sh);
    float yb = __fadd_rn(__fmul_rn(b, iv), sh);
    m4 = fmaxf(m4, fmaxf(fabsf(ya), fabsf(yb)));
  }
  m4 = wave_max(m4);
  __syncthreads();
  if ((tid & 63) == 0) sred[tid >> 6] = m4;
  __syncthreads();
  if (tid == 0)
    sc[3] = __float_as_uint(fmaxf(fmaxf(sred[0], sred[1]), fmaxf(sred[2], sred[3])) / 127.0f);
}

// ---------------- K6: final quant-dequant write + act_scale (4 indep loads) ----------------
__global__ void k_final(const signed char* __restrict__ k1, const uint* __restrict__ sc,
                        const float* __restrict__ inv_, const float* __restrict__ shf,
                        float* __restrict__ out) {
  __shared__ float tab[255];
  const float s1 = __uint_as_float(sc[1]) / 127.0f;
  const float s2 = __uint_as_float(sc[2]);
  const float s3 = __uint_as_float(sc[3]);
  for (int t = threadIdx.x; t < 255; t += 256) {
    float y1 = (float)(t - 127) * s1;
    float e = erff(y1 * 0.70710678118654752f);
    float y2 = (y1 * (e + 1.0f)) * 0.5f;
    float q2 = fminf(fmaxf(rintf(y2 / s2), -127.f), 127.f);
    tab[t] = q2 * s2;
  }
  __syncthreads();
  const int i = blockIdx.x * 256 + threadIdx.x;   // 4704 blocks, stride 1204224
  const char4* k4 = (const char4*)k1;
  char4 a0 = k4[i];
  char4 a1 = k4[i + 1204224];
  char4 a2 = k4[i + 2 * 1204224];
  char4 a3 = k4[i + 3 * 1204224];
  float4* out4 = (float4*)out;
#define FIN(kk, idx)                                                       \
  {                                                                        \
    int c = ((idx) / 49) % 768;                                            \
    float iv = inv_[c], sh = shf[c];                                       \
    float fa = __fadd_rn(__fmul_rn(tab[kk.x + 127], iv), sh);              \
    float fb = __fadd_rn(__fmul_rn(tab[kk.y + 127], iv), sh);              \
    float fc = __fadd_rn(__fmul_rn(tab[kk.z + 127], iv), sh);              \
    float fd = __fadd_rn(__fmul_rn(tab[kk.w + 127], iv), sh);              \
    float4 o;                                                              \
    o.x = fminf(fmaxf(rintf(fa / s3), -127.f), 127.f) * s3;                \
    o.y = fminf(fmaxf(rintf(fb / s3), -127.f), 127.f) * s3;                \
    o.z = fminf(fmaxf(rintf(fc / s3), -127.f), 127.f) * s3;                \
    o.w = fminf(fmaxf(rintf(fd / s3), -127.f), 127.f) * s3;                \
    out4[idx] = o;                                                         \
  }
  FIN(a0, i)
  FIN(a1, i + 1204224)
  FIN(a2, i + 2 * 1204224)
  FIN(a3, i + 3 * 1204224)
#undef FIN
  if (blockIdx.x == 0 && threadIdx.x == 0) out[TOT] = s3;  // act_scale
}

extern "C" void kernel_launch(void* const* d_in, const int* in_sizes, int n_in,
                              void* d_out, int out_size, void* d_ws, size_t ws_size,
                              hipStream_t stream) {
  const float* x     = (const float*)d_in[0];
  const float* W     = (const float*)d_in[1];
  const float* bias  = (const float*)d_in[2];
  const float* gamma = (const float*)d_in[3];
  const float* beta  = (const float*)d_in[4];
  const float* rmean = (const float*)d_in[5];
  const float* rvar  = (const float*)d_in[6];
  float* out = (float*)d_out;
  char* ws = (char*)d_ws;

  signed char* aq  = (signed char*)(ws + OFF_AQ);
  signed char* wq  = (signed char*)(ws + OFF_WQ);
  float* wsc  = (float*)(ws + OFF_WSC);
  float* inv_ = (float*)(ws + OFF_INV);
  float* shf  = (float*)(ws + OFF_SHF);
  float* pA   = (float*)(ws + OFF_PA);
  float* pB   = (float*)(ws + OFF_PB);
  float* cmn  = (float*)(ws + OFF_CMN);
  float* cmx  = (float*)(ws + OFF_CMX);
  uint*  sc   = (uint*)(ws + OFF_SC);
  signed char* k1 = (signed char*)(ws + OFF_AQ);  // aliases aq (dead after GEMM)

  k_maxabs<<<1176, 256, 0, stream>>>(x, pA);
  k_wquant<<<768, 256, 0, stream>>>(W, gamma, beta, rmean, rvar, wq, wsc, inv_, shf);
  k_combine<<<1, 256, 0, stream>>>(pA, 1176, sc + 0);
  k_im2col<<<4704, 256, 0, stream>>>(x, sc, aq);
  k_gemm<<<1176, 256, 0, stream>>>(aq, wq, bias, wsc, sc, out, pB);
  k_combine<<<1, 256, 0, stream>>>(pB, 1176, sc + 1);
  k_gelu_chan<<<768, 256, 0, stream>>>(out, sc, k1, cmn, cmx);
  k_scales<<<1, 256, 0, stream>>>(cmn, cmx, inv_, shf, sc);
  k_final<<<4704, 256, 0, stream>>>(k1, sc, inv_, shf, out);
}